// Round 2
// baseline (259.795 us; speedup 1.0000x reference)
//
#include <hip/hip_runtime.h>

// Problem constants (match setup_inputs): B=64, S=4096, H=128, K=16.
// Reference reduces to: y = circular_depthwise_conv16(x, w) / 64;
//   h = y + x;  out = ln_w * (h - mean_H(h)) / sqrt(var_H(h) + 1e-12) + ln_b
// (ortho rfft * ortho rfft -> ortho irfft nets a 1/sqrt(S) = 1/64 scale.)

constexpr int S = 4096;
constexpr int H = 128;
constexpr int K = 16;
constexpr int CHUNK = 64;   // seq rows per wave
constexpr int GROUP = 16;   // rows loaded per batch (== K, ring size)

__global__ __launch_bounds__(256)
void fconv_ln_kernel(const float* __restrict__ x,      // [B,S,H]
                     const float* __restrict__ wconv,  // [K,H]
                     const float* __restrict__ lnw,    // [H]
                     const float* __restrict__ lnb,    // [H]
                     float* __restrict__ out)          // [B,S,H]
{
    const int wid  = (blockIdx.x * blockDim.x + threadIdx.x) >> 6;
    const int lane = threadIdx.x & 63;

    const int chunksPerSeq = S / CHUNK;            // 64
    const int b  = wid / chunksPerSeq;
    const int t0 = (wid % chunksPerSeq) * CHUNK;

    const int c2 = lane * 2;                       // channel pair base

    // conv weights for this lane's 2 channels (16 float2 = 32 VGPR)
    float2 w[K];
#pragma unroll
    for (int k = 0; k < K; ++k)
        w[k] = *reinterpret_cast<const float2*>(&wconv[k * H + c2]);

    const float2 gamma = *reinterpret_cast<const float2*>(&lnw[c2]);
    const float2 beta  = *reinterpret_cast<const float2*>(&lnb[c2]);

    const float* xb = x   + (size_t)b * S * H;
    float*       ob = out + (size_t)b * S * H;

    // ring[0..15]  : rows t0+tb-16 .. t0+tb-1  (sliding history)
    // ring[16..31] : rows t0+tb    .. t0+tb+15 (current group)
    float2 ring[2 * GROUP];

    // preamble: history rows (circular wrap)
#pragma unroll
    for (int s = 0; s < GROUP; ++s) {
        int t = (t0 - GROUP + s + S) & (S - 1);
        ring[s] = *reinterpret_cast<const float2*>(&xb[(size_t)t * H + c2]);
    }

    for (int tb = 0; tb < CHUNK; tb += GROUP) {
        // issue all 16 independent row loads up front (latency hiding)
#pragma unroll
        for (int j = 0; j < GROUP; ++j) {
            ring[GROUP + j] = *reinterpret_cast<const float2*>(
                &xb[(size_t)(t0 + tb + j) * H + c2]);
        }

#pragma unroll
        for (int j = 0; j < GROUP; ++j) {
            // depthwise circular conv: x[t-k] lives at ring[16 + j - k]
            float ax = 0.f, ay = 0.f;
#pragma unroll
            for (int k = 0; k < K; ++k) {
                const float2 v = ring[GROUP + j - k];
                ax = fmaf(w[k].x, v.x, ax);
                ay = fmaf(w[k].y, v.y, ay);
            }
            const float2 xt = ring[GROUP + j];
            // h = conv/64 + x
            float hx = fmaf(ax, 0.015625f, xt.x);
            float hy = fmaf(ay, 0.015625f, xt.y);

            // LayerNorm over H=128 via 64-lane butterfly (2 moments)
            float s1 = hx + hy;
            float s2 = hx * hx + hy * hy;
#pragma unroll
            for (int m = 1; m < 64; m <<= 1) {
                s1 += __shfl_xor(s1, m, 64);
                s2 += __shfl_xor(s2, m, 64);
            }
            const float u   = s1 * (1.0f / H);
            const float var = fmaf(s2, 1.0f / H, -u * u);
            const float inv = rsqrtf(var + 1e-12f);

            float2 o;
            o.x = fmaf(gamma.x * inv, hx - u, beta.x);
            o.y = fmaf(gamma.y * inv, hy - u, beta.y);
            *reinterpret_cast<float2*>(&ob[(size_t)(t0 + tb + j) * H + c2]) = o;
        }

        // slide the window: current group becomes history
#pragma unroll
        for (int j = 0; j < GROUP; ++j)
            ring[j] = ring[GROUP + j];
    }
}

extern "C" void kernel_launch(void* const* d_in, const int* in_sizes, int n_in,
                              void* d_out, int out_size, void* d_ws, size_t ws_size,
                              hipStream_t stream)
{
    const float* x     = (const float*)d_in[0];   // [64,4096,128]
    const float* wconv = (const float*)d_in[1];   // [1,16,128]
    const float* lnw   = (const float*)d_in[2];   // [128]
    const float* lnb   = (const float*)d_in[3];   // [128]
    float*       out   = (float*)d_out;

    const int Bsz = in_sizes[0] / (S * H);        // 64
    const int totalWaves = Bsz * (S / CHUNK);     // 4096
    const int threads = 256;
    const int blocks  = totalWaves * 64 / threads; // 1024

    hipLaunchKernelGGL(fconv_ln_kernel, dim3(blocks), dim3(threads), 0, stream,
                       x, wconv, lnw, lnb, out);
}

// Round 3
// 242.976 us; speedup vs baseline: 1.0692x; 1.0692x over previous
//
#include <hip/hip_runtime.h>

// Reference reduces to: y = circular_depthwise_conv16(x, w) / 64;
//   h = y + x;  out = ln_w * (h - mean_H(h)) / sqrt(var_H(h) + 1e-12) + ln_b
// (ortho rfft * ortho rfft -> ortho irfft nets a 1/sqrt(S) = 1/64 scale.)
//
// R3: LN reduction via DPP (VALU pipe, full rate) instead of __shfl_xor
// (ds_swizzle, LDS-latency chains) — R2 was latency-bound at 27% HBM.
// Plus explicit next-group prefetch (G=8) so HBM latency hides under compute.

constexpr int S = 4096;
constexpr int H = 128;
constexpr int K = 16;
constexpr int CHUNK = 64;   // seq rows per wave (halo amp = 16/64 = +25% reads)
constexpr int G = 8;        // rows per compute group / prefetch batch

// x + dpp_perm(x); disabled/invalid lanes contribute 0 (old=0, bound_ctrl=1)
template <int CTRL, int ROWMASK>
__device__ __forceinline__ float dpp_add(float x) {
    int y = __builtin_amdgcn_update_dpp(0, __float_as_int(x), CTRL, ROWMASK, 0xf, true);
    return x + __int_as_float(y);
}

// Sum over 64 lanes, broadcast to all lanes. 6 full-rate VALU adds + readlane.
__device__ __forceinline__ float wave_sum(float x) {
    x = dpp_add<0x111, 0xf>(x);  // row_shr:1
    x = dpp_add<0x112, 0xf>(x);  // row_shr:2
    x = dpp_add<0x114, 0xf>(x);  // row_shr:4
    x = dpp_add<0x118, 0xf>(x);  // row_shr:8  -> lane 15/31/47/63 = row sums
    x = dpp_add<0x142, 0xa>(x);  // row_bcast15 -> rows 1,3
    x = dpp_add<0x143, 0xc>(x);  // row_bcast31 -> rows 2,3; lane 63 = total
    return __int_as_float(__builtin_amdgcn_readlane(__float_as_int(x), 63));
}

__global__ __launch_bounds__(256)
void fconv_ln_kernel(const float* __restrict__ x,      // [B,S,H]
                     const float* __restrict__ wconv,  // [K,H]
                     const float* __restrict__ lnw,    // [H]
                     const float* __restrict__ lnb,    // [H]
                     float* __restrict__ out)          // [B,S,H]
{
    const int wid  = (blockIdx.x * blockDim.x + threadIdx.x) >> 6;
    const int lane = threadIdx.x & 63;

    const int chunksPerSeq = S / CHUNK;            // 64
    const int b  = wid / chunksPerSeq;
    const int t0 = (wid % chunksPerSeq) * CHUNK;

    const int c2 = lane * 2;                       // this lane's channel pair

    float2 w[K];                                   // 32 VGPR
#pragma unroll
    for (int k = 0; k < K; ++k)
        w[k] = *reinterpret_cast<const float2*>(&wconv[k * H + c2]);

    const float2 gamma = *reinterpret_cast<const float2*>(&lnw[c2]);
    const float2 beta  = *reinterpret_cast<const float2*>(&lnb[c2]);

    const float* xb = x   + (size_t)b * S * H;
    float*       ob = out + (size_t)b * S * H;

    float2 hist[K];    // rows (groupStart-16 .. groupStart-1)
    float2 cur[G];     // rows (groupStart .. groupStart+G-1)
    float2 nxt[G];     // prefetch of the next group

    // preamble: history (circular wrap) + group 0
#pragma unroll
    for (int s = 0; s < K; ++s) {
        int t = (t0 - K + s + S) & (S - 1);
        hist[s] = *reinterpret_cast<const float2*>(&xb[(size_t)t * H + c2]);
    }
#pragma unroll
    for (int j = 0; j < G; ++j)
        cur[j] = *reinterpret_cast<const float2*>(&xb[(size_t)(t0 + j) * H + c2]);

    for (int tb = 0; tb < CHUNK; tb += G) {
        // prefetch next group before touching current one (HBM latency hiding)
        if (tb + G < CHUNK) {
#pragma unroll
            for (int j = 0; j < G; ++j)
                nxt[j] = *reinterpret_cast<const float2*>(
                    &xb[(size_t)(t0 + tb + G + j) * H + c2]);
        }

#pragma unroll
        for (int j = 0; j < G; ++j) {
            // x[t-k]: k<=j -> cur[j-k]; k>j -> hist[K + j - k]   (static idx)
            float ax = 0.f, ay = 0.f;
#pragma unroll
            for (int k = 0; k < K; ++k) {
                const float2 v = (k <= j) ? cur[j - k] : hist[K + j - k];
                ax = fmaf(w[k].x, v.x, ax);
                ay = fmaf(w[k].y, v.y, ay);
            }
            const float2 xt = cur[j];
            float hx = fmaf(ax, 0.015625f, xt.x);   // conv/64 + residual
            float hy = fmaf(ay, 0.015625f, xt.y);

            // LayerNorm over H=128: two DPP allreduces (VALU pipe)
            const float s1 = wave_sum(hx + hy);
            const float s2 = wave_sum(hx * hx + hy * hy);
            const float u   = s1 * (1.0f / H);
            const float var = fmaf(s2, 1.0f / H, -u * u);
            const float inv = rsqrtf(var + 1e-12f);

            float2 o;
            o.x = fmaf(gamma.x * inv, hx - u, beta.x);
            o.y = fmaf(gamma.y * inv, hy - u, beta.y);
            *reinterpret_cast<float2*>(&ob[(size_t)(t0 + tb + j) * H + c2]) = o;
        }

        // slide window: hist <- {hist[G..], cur}; cur <- nxt   (static copies)
#pragma unroll
        for (int s = 0; s < K - G; ++s) hist[s] = hist[s + G];
#pragma unroll
        for (int j = 0; j < G; ++j)     hist[K - G + j] = cur[j];
#pragma unroll
        for (int j = 0; j < G; ++j)     cur[j] = nxt[j];
    }
}

extern "C" void kernel_launch(void* const* d_in, const int* in_sizes, int n_in,
                              void* d_out, int out_size, void* d_ws, size_t ws_size,
                              hipStream_t stream)
{
    const float* x     = (const float*)d_in[0];   // [64,4096,128]
    const float* wconv = (const float*)d_in[1];   // [1,16,128]
    const float* lnw   = (const float*)d_in[2];   // [128]
    const float* lnb   = (const float*)d_in[3];   // [128]
    float*       out   = (float*)d_out;

    const int Bsz = in_sizes[0] / (S * H);        // 64
    const int totalWaves = Bsz * (S / CHUNK);     // 4096
    const int threads = 256;
    const int blocks  = totalWaves * 64 / threads; // 1024

    hipLaunchKernelGGL(fconv_ln_kernel, dim3(blocks), dim3(threads), 0, stream,
                       x, wconv, lnw, lnb, out);
}

// Round 4
// 241.752 us; speedup vs baseline: 1.0746x; 1.0051x over previous
//
#include <hip/hip_runtime.h>

// Reference reduces to: y = circular_depthwise_conv16(x, w) / 64;
//   h = y + x;  out = ln_w * (h - mean_H(h)) / sqrt(var_H(h) + 1e-12) + ln_b
// (ortho rfft * ortho rfft -> ortho irfft nets a 1/sqrt(S) = 1/64 scale.)
//
// R4: __launch_bounds__(256,4) — R3's allocator squeezed to 64 VGPR (8-wave
// boundary) and destroyed the register prefetch (load folded into use with
// vmcnt(0) waits -> latency-bound at 31% HBM, VALUBusy 28%). A 128-VGPR
// budget keeps w[16]+hist[16]+cur[8]+nxt[8] resident so the 8 prefetch loads
// stay in flight under the group's ~480cy of compute. Plus non-temporal
// stores so the 134MB output stream doesn't evict the L3-resident input.

constexpr int S = 4096;
constexpr int H = 128;
constexpr int K = 16;
constexpr int CHUNK = 64;   // seq rows per wave (halo amp = +25% reads, L3-hit)
constexpr int G = 8;        // rows per compute group / prefetch batch

typedef float v2f __attribute__((ext_vector_type(2)));

// x + dpp_perm(x); disabled/invalid lanes contribute 0 (old=0, bound_ctrl=1)
template <int CTRL, int ROWMASK>
__device__ __forceinline__ float dpp_add(float x) {
    int y = __builtin_amdgcn_update_dpp(0, __float_as_int(x), CTRL, ROWMASK, 0xf, true);
    return x + __int_as_float(y);
}

// Sum over 64 lanes, broadcast to all lanes. 6 full-rate VALU adds + readlane.
__device__ __forceinline__ float wave_sum(float x) {
    x = dpp_add<0x111, 0xf>(x);  // row_shr:1
    x = dpp_add<0x112, 0xf>(x);  // row_shr:2
    x = dpp_add<0x114, 0xf>(x);  // row_shr:4
    x = dpp_add<0x118, 0xf>(x);  // row_shr:8  -> lane 15/31/47/63 = row sums
    x = dpp_add<0x142, 0xa>(x);  // row_bcast15 -> rows 1,3
    x = dpp_add<0x143, 0xc>(x);  // row_bcast31 -> rows 2,3; lane 63 = total
    return __int_as_float(__builtin_amdgcn_readlane(__float_as_int(x), 63));
}

__global__ __launch_bounds__(256, 4)
void fconv_ln_kernel(const float* __restrict__ x,      // [B,S,H]
                     const float* __restrict__ wconv,  // [K,H]
                     const float* __restrict__ lnw,    // [H]
                     const float* __restrict__ lnb,    // [H]
                     float* __restrict__ out)          // [B,S,H]
{
    const int wid  = (blockIdx.x * blockDim.x + threadIdx.x) >> 6;
    const int lane = threadIdx.x & 63;

    const int chunksPerSeq = S / CHUNK;            // 64
    const int b  = wid / chunksPerSeq;
    const int t0 = (wid % chunksPerSeq) * CHUNK;

    const int c2 = lane * 2;                       // this lane's channel pair

    float2 w[K];                                   // 32 VGPR
#pragma unroll
    for (int k = 0; k < K; ++k)
        w[k] = *reinterpret_cast<const float2*>(&wconv[k * H + c2]);

    const float2 gamma = *reinterpret_cast<const float2*>(&lnw[c2]);
    const float2 beta  = *reinterpret_cast<const float2*>(&lnb[c2]);

    const float* xb = x   + (size_t)b * S * H;
    float*       ob = out + (size_t)b * S * H;

    float2 hist[K];    // rows (groupStart-16 .. groupStart-1)   32 VGPR
    float2 cur[G];     // rows (groupStart .. groupStart+G-1)    16 VGPR
    float2 nxt[G];     // prefetch of the next group             16 VGPR

    // preamble: history (circular wrap) + group 0
#pragma unroll
    for (int s = 0; s < K; ++s) {
        int t = (t0 - K + s + S) & (S - 1);
        hist[s] = *reinterpret_cast<const float2*>(&xb[(size_t)t * H + c2]);
    }
#pragma unroll
    for (int j = 0; j < G; ++j)
        cur[j] = *reinterpret_cast<const float2*>(&xb[(size_t)(t0 + j) * H + c2]);

    for (int tb = 0; tb < CHUNK; tb += G) {
        // prefetch next group before touching current one (HBM latency hiding)
        if (tb + G < CHUNK) {
#pragma unroll
            for (int j = 0; j < G; ++j)
                nxt[j] = *reinterpret_cast<const float2*>(
                    &xb[(size_t)(t0 + tb + G + j) * H + c2]);
        }

#pragma unroll
        for (int j = 0; j < G; ++j) {
            // x[t-k]: k<=j -> cur[j-k]; k>j -> hist[K + j - k]   (static idx)
            float ax = 0.f, ay = 0.f;
#pragma unroll
            for (int k = 0; k < K; ++k) {
                const float2 v = (k <= j) ? cur[j - k] : hist[K + j - k];
                ax = fmaf(w[k].x, v.x, ax);
                ay = fmaf(w[k].y, v.y, ay);
            }
            const float2 xt = cur[j];
            float hx = fmaf(ax, 0.015625f, xt.x);   // conv/64 + residual
            float hy = fmaf(ay, 0.015625f, xt.y);

            // LayerNorm over H=128: two DPP allreduces (VALU pipe)
            const float s1 = wave_sum(hx + hy);
            const float s2 = wave_sum(hx * hx + hy * hy);
            const float u   = s1 * (1.0f / H);
            const float var = fmaf(s2, 1.0f / H, -u * u);
            const float inv = rsqrtf(var + 1e-12f);

            v2f o;
            o.x = fmaf(gamma.x * inv, hx - u, beta.x);
            o.y = fmaf(gamma.y * inv, hy - u, beta.y);
            // non-temporal: don't evict the L3-resident input with the output stream
            __builtin_nontemporal_store(
                o, reinterpret_cast<v2f*>(&ob[(size_t)(t0 + tb + j) * H + c2]));
        }

        // slide window: hist <- {hist[G..], cur}; cur <- nxt   (static copies)
#pragma unroll
        for (int s = 0; s < K - G; ++s) hist[s] = hist[s + G];
#pragma unroll
        for (int j = 0; j < G; ++j)     hist[K - G + j] = cur[j];
#pragma unroll
        for (int j = 0; j < G; ++j)     cur[j] = nxt[j];
    }
}

extern "C" void kernel_launch(void* const* d_in, const int* in_sizes, int n_in,
                              void* d_out, int out_size, void* d_ws, size_t ws_size,
                              hipStream_t stream)
{
    const float* x     = (const float*)d_in[0];   // [64,4096,128]
    const float* wconv = (const float*)d_in[1];   // [1,16,128]
    const float* lnw   = (const float*)d_in[2];   // [128]
    const float* lnb   = (const float*)d_in[3];   // [128]
    float*       out   = (float*)d_out;

    const int Bsz = in_sizes[0] / (S * H);        // 64
    const int totalWaves = Bsz * (S / CHUNK);     // 4096
    const int threads = 256;
    const int blocks  = totalWaves * 64 / threads; // 1024

    hipLaunchKernelGGL(fconv_ln_kernel, dim3(blocks), dim3(threads), 0, stream,
                       x, wconv, lnw, lnb, out);
}